// Round 6
// baseline (439.863 us; speedup 1.0000x reference)
//
#include <hip/hip_runtime.h>
#include <hip/hip_bf16.h>
#include <cstdint>
#include <cstddef>

#define B_  64
#define S_  2048
#define E_  512
#define C_  512
#define H_  256

using f32x4 = __attribute__((ext_vector_type(4))) float;
using s16x8 = __attribute__((ext_vector_type(8))) short;

// packed fp32x4 -> bf16x4 (RNE)
__device__ __forceinline__ uint2 f4_to_bf4(float4 v) {
    __hip_bfloat162 lo = __float22bfloat162_rn(make_float2(v.x, v.y));
    __hip_bfloat162 hi = __float22bfloat162_rn(make_float2(v.z, v.w));
    union { __hip_bfloat162 b; unsigned u; } a, c;
    a.b = lo; c.b = hi;
    return make_uint2(a.u, c.u);
}

// 8 fp32 (two f32x4) -> bf16x8 fragment
__device__ __forceinline__ s16x8 cvt8(f32x4 lo, f32x4 hi) {
    union { __hip_bfloat162 b; unsigned u; } p0, p1, p2, p3;
    p0.b = __float22bfloat162_rn(make_float2(lo[0], lo[1]));
    p1.b = __float22bfloat162_rn(make_float2(lo[2], lo[3]));
    p2.b = __float22bfloat162_rn(make_float2(hi[0], hi[1]));
    p3.b = __float22bfloat162_rn(make_float2(hi[2], hi[3]));
    union { unsigned u[4]; s16x8 s; } r;
    r.u[0] = p0.u; r.u[1] = p1.u; r.u[2] = p2.u; r.u[3] = p3.u;
    return r.s;
}

// async global->LDS DMA, 16 B per lane; lds dest = wave-uniform base + lane*16
__device__ __forceinline__ void async16(const void* g, void* l) {
    __builtin_amdgcn_global_load_lds(
        (const __attribute__((address_space(1))) void*)g,
        (__attribute__((address_space(3))) void*)l,
        16, 0, 0);
}

// ---- prep: convert W_word to bf16 in ws ----
__global__ void prep_w(const float* __restrict__ W, unsigned short* __restrict__ Wb) {
    int i = (blockIdx.x * 256 + threadIdx.x) * 4;
    float4 v = *(const float4*)(W + i);
    uint2 o = f4_to_bf4(v);
    *(uint2*)(Wb + i) = o;
}

// ---- prep: cb[b][h] = ctx[b]@W_ctx[h]^T + b_ctx[h] + b_word[h] ----
__global__ void prep_ctx(const float* __restrict__ ctx, const float* __restrict__ Wc,
                         const float* __restrict__ bc, const float* __restrict__ bw,
                         float* __restrict__ cb) {
    __shared__ float row[C_];
    int b = blockIdx.x, t = threadIdx.x;
    row[t] = ctx[b * C_ + t];
    row[t + 256] = ctx[b * C_ + t + 256];
    __syncthreads();
    const float4* w4 = (const float4*)(Wc + (size_t)t * C_);
    const float4* x4 = (const float4*)row;
    float acc = 0.f;
    #pragma unroll 4
    for (int c = 0; c < C_ / 4; ++c) {
        float4 w = w4[c], x = x4[c];
        acc += w.x * x.x + w.y * x.y + w.z * x.z + w.w * x.w;
    }
    cb[b * H_ + t] = acc + bc[t] + bw[t];
}

// ---- main: scores[b,s] = w_hidden . tanh(embeds[b,s]@W_word^T + cb[b]) ----
// global_load_lds DMA staging for BOTH tiles (m97 pattern). XOR swizzle in the
// global->lane mapping (LDS chunk p of row r = global chunk p^(r&mask)) keeps
// ds_read_b128 at minimal 8-phase banking with no padding (DMA forbids pads).
// A staged as raw fp32; converted to bf16 after the LDS fragment read.
#define BM 128
#define BN 256
#define BK 64

__global__ __launch_bounds__(512) void scores_kernel(
    const float* __restrict__ A,            // [B*S, E] fp32
    const unsigned short* __restrict__ Wb,  // [H, E] bf16
    const float* __restrict__ cb,           // [B, H]
    const float* __restrict__ wh,           // [H]
    const int*   __restrict__ lens,         // [B]
    float* __restrict__ scores)             // [B*S]
{
    __shared__ __align__(16) float At[BM * 64];           // 32 KB: 128 rows x 64 fp32 (16 chunks)
    __shared__ __align__(16) unsigned short Bt[BN * 64];  // 32 KB: 256 rows x 64 bf16 (8 chunks)
    __shared__ float sblk[BM];
    int t = threadIdx.x;
    int m0 = blockIdx.x * BM;
    int b  = m0 >> 11;   // /S_
    int ms = m0 & (S_ - 1);
    if (ms >= lens[b]) return;   // fully-masked slab: dead work

    int w = t >> 6, lane = t & 63, quad = lane >> 4, lm = lane & 15;
    int wm = (w & 1) * 64, wn = (w >> 1) * 64;

    if (t < BM) sblk[t] = 0.f;

    f32x4 acc[4][4] = {};

    int la16 = lane >> 4, lc16 = lane & 15;  // A DMA: 4 rows/inst, 16 chunks/row
    int la8  = lane >> 3, lc8  = lane & 7;   // B DMA: 8 rows/inst, 8 chunks/row

    for (int k0 = 0; k0 < E_; k0 += BK) {
        // A: 8 waves x 4 insts -> 128 rows x 256 B
        #pragma unroll
        for (int j = 0; j < 4; ++j) {
            int r  = (w << 4) + (j << 2) + la16;
            int cg = (lc16 ^ (r & 15)) << 2;             // swizzled global float offset
            async16(A + (size_t)(m0 + r) * E_ + k0 + cg,
                    (char*)At + (((w << 4) + (j << 2)) << 8));
        }
        // B: 8 waves x 4 insts -> 256 rows x 128 B
        #pragma unroll
        for (int j = 0; j < 4; ++j) {
            int r  = (w << 5) + (j << 3) + la8;
            int cg = (lc8 ^ (r & 7)) << 3;               // swizzled global short offset
            async16(Wb + (size_t)r * E_ + k0 + cg,
                    (char*)Bt + (((w << 5) + (j << 3)) << 7));
        }
        __syncthreads();
        #pragma unroll
        for (int ks = 0; ks < 2; ++ks) {
            s16x8 af[4], bfr[4];
            #pragma unroll
            for (int i = 0; i < 4; ++i) {
                int r = wm + i * 16 + lm;
                int x = r & 15;
                int c0 = (ks * 8 + quad * 2) ^ x;
                int c1 = (ks * 8 + quad * 2 + 1) ^ x;
                f32x4 lo = *(const f32x4*)(At + r * 64 + c0 * 4);
                f32x4 hi = *(const f32x4*)(At + r * 64 + c1 * 4);
                af[i] = cvt8(lo, hi);
            }
            #pragma unroll
            for (int i = 0; i < 4; ++i) {
                int r = wn + i * 16 + lm;
                int c = (ks * 4 + quad) ^ (r & 7);
                bfr[i] = *(const s16x8*)(Bt + r * 64 + c * 8);
            }
            #pragma unroll
            for (int mi = 0; mi < 4; ++mi)
                #pragma unroll
                for (int ni = 0; ni < 4; ++ni)
                    acc[mi][ni] = __builtin_amdgcn_mfma_f32_16x16x32_bf16(
                        af[mi], bfr[ni], acc[mi][ni], 0, 0, 0);
        }
        __syncthreads();
    }

    float wv[4], cbv[4];
    #pragma unroll
    for (int ni = 0; ni < 4; ++ni) {
        int n = wn + ni * 16 + lm;
        wv[ni]  = wh[n];
        cbv[ni] = cb[b * H_ + n];
    }
    #pragma unroll
    for (int mi = 0; mi < 4; ++mi) {
        #pragma unroll
        for (int r = 0; r < 4; ++r) {
            float p = 0.f;
            #pragma unroll
            for (int ni = 0; ni < 4; ++ni) {
                float x = acc[mi][ni][r] + cbv[ni];
                x = fminf(fmaxf(x, -15.f), 15.f);
                float e = __expf(2.f * x);
                float th = 1.f - 2.f * __builtin_amdgcn_rcpf(e + 1.f);
                p += wv[ni] * th;
            }
            #pragma unroll
            for (int off = 8; off >= 1; off >>= 1)
                p += __shfl_xor(p, off);
            if (lm == 0)
                atomicAdd(&sblk[wm + mi * 16 + quad * 4 + r], p);
        }
    }
    __syncthreads();
    if (t < BM) scores[m0 + t] = sblk[t];
}

// ---- masked softmax over s<len; attn=0 for s>=len. (1e-10*z term dropped:
// rel err <= ~4e-6, far under threshold; rows s>=len never read.)
__global__ void softmax_kernel(const int* __restrict__ lens, float* __restrict__ attn) {
    __shared__ float redm[4], redt[4];
    int b = blockIdx.x, t = threadIdx.x;
    int len = lens[b];
    float* sc = attn + (size_t)b * S_;
    float v[8];
    #pragma unroll
    for (int i = 0; i < 8; ++i) {
        int s = t + i * 256;
        v[i] = (s < len) ? sc[s] : -1e30f;
    }
    float m = -1e30f;
    #pragma unroll
    for (int i = 0; i < 8; ++i) m = fmaxf(m, v[i]);
    #pragma unroll
    for (int off = 32; off >= 1; off >>= 1) m = fmaxf(m, __shfl_xor(m, off));
    if ((t & 63) == 0) redm[t >> 6] = m;
    __syncthreads();
    m = fmaxf(fmaxf(redm[0], redm[1]), fmaxf(redm[2], redm[3]));
    float e[8]; float tm = 0.f;
    #pragma unroll
    for (int i = 0; i < 8; ++i) {
        int s = t + i * 256;
        e[i] = (s < len) ? __expf(v[i] - m) : 0.f;
        tm += e[i];
    }
    #pragma unroll
    for (int off = 32; off >= 1; off >>= 1) tm += __shfl_xor(tm, off);
    if ((t & 63) == 0) redt[t >> 6] = tm;
    __syncthreads();
    tm = redt[0] + redt[1] + redt[2] + redt[3];
    float sfac = 1.f / tm;
    #pragma unroll
    for (int i = 0; i < 8; ++i) {
        int s = t + i * 256;
        sc[s] = e[i] * sfac;
    }
}

// ---- attention_features[b,e] = sum_{s<len} attn[b,s]*embeds[b,s,e] ----
__global__ __launch_bounds__(512) void wsum_kernel(
    const float* __restrict__ A, const float* __restrict__ attn,
    const int* __restrict__ lens, float* __restrict__ out) {
    int b = blockIdx.y;
    int len = lens[b];
    int s0 = blockIdx.x * 128;
    if (s0 >= len) return;
    int send = s0 + 128; if (send > len) send = len;
    int t  = threadIdx.x;
    int e4 = t & 127;   // float4 column
    int sr = t >> 7;    // row group 0..3
    const float* ap = attn + (size_t)b * S_;
    f32x4 acc = {0.f, 0.f, 0.f, 0.f};
    const float* base = A + (size_t)b * S_ * E_;
    for (int s = s0 + sr; s < send; s += 4) {
        float wgt = ap[s];
        f32x4 v = *(const f32x4*)(base + (size_t)s * E_ + e4 * 4);
        acc += wgt * v;
    }
    __shared__ f32x4 red[4][128];
    red[sr][e4] = acc;
    __syncthreads();
    if (t < 128) {
        f32x4 tot = red[0][t] + red[1][t] + red[2][t] + red[3][t];
        float* o = out + (size_t)b * E_ + t * 4;
        atomicAdd(o + 0, tot[0]);
        atomicAdd(o + 1, tot[1]);
        atomicAdd(o + 2, tot[2]);
        atomicAdd(o + 3, tot[3]);
    }
}

extern "C" void kernel_launch(void* const* d_in, const int* in_sizes, int n_in,
                              void* d_out, int out_size, void* d_ws, size_t ws_size,
                              hipStream_t stream) {
    const float* embeds = (const float*)d_in[0];
    const int*   lens   = (const int*)d_in[1];
    const float* ctx    = (const float*)d_in[2];
    const float* Ww     = (const float*)d_in[3];
    const float* bw     = (const float*)d_in[4];
    const float* Wc     = (const float*)d_in[5];
    const float* bc     = (const float*)d_in[6];
    const float* wh     = (const float*)d_in[7];
    float* out  = (float*)d_out;
    float* feat = out;                 // [B, E]
    float* attn = out + B_ * E_;       // [B, S] (raw scores, then attn; 0 for s>=len)

    unsigned short* Wb = (unsigned short*)d_ws;                                  // 256 KB
    float* cb = (float*)((char*)d_ws + (size_t)H_ * E_ * sizeof(unsigned short)); // 64 KB

    hipMemsetAsync(feat, 0, (size_t)B_ * E_ * sizeof(float), stream);
    prep_w<<<(H_ * E_) / 1024, 256, 0, stream>>>(Ww, Wb);
    prep_ctx<<<B_, 256, 0, stream>>>(ctx, Wc, bc, bw, cb);
    scores_kernel<<<dim3(B_ * S_ / BM), 512, 0, stream>>>(embeds, Wb, cb, wh, lens, attn);
    softmax_kernel<<<B_, 256, 0, stream>>>(lens, attn);
    wsum_kernel<<<dim3(S_ / 128, B_), 512, 0, stream>>>(embeds, attn, lens, feat);
}

// Round 7
// 407.681 us; speedup vs baseline: 1.0789x; 1.0789x over previous
//
#include <hip/hip_runtime.h>
#include <hip/hip_bf16.h>
#include <cstdint>
#include <cstddef>

#define B_  64
#define S_  2048
#define E_  512
#define C_  512
#define H_  256

using f32x4 = __attribute__((ext_vector_type(4))) float;
using s16x8 = __attribute__((ext_vector_type(8))) short;

// packed fp32x4 -> bf16x4 (RNE)
__device__ __forceinline__ uint2 f4_to_bf4(float4 v) {
    __hip_bfloat162 lo = __float22bfloat162_rn(make_float2(v.x, v.y));
    __hip_bfloat162 hi = __float22bfloat162_rn(make_float2(v.z, v.w));
    union { __hip_bfloat162 b; unsigned u; } a, c;
    a.b = lo; c.b = hi;
    return make_uint2(a.u, c.u);
}

// async global->LDS DMA, 16 B per lane; lds dest = wave-uniform base + lane*16
__device__ __forceinline__ void async16(const void* g, void* l) {
    __builtin_amdgcn_global_load_lds(
        (const __attribute__((address_space(1))) void*)g,
        (__attribute__((address_space(3))) void*)l,
        16, 0, 0);
}

// ---- merged prep: blocks 0..127 convert W_word to bf16; blocks 128..191 do
// cb[b][h] = ctx[b]@W_ctx[h]^T + b_ctx[h] + b_word[h] ----
__global__ void prep_kernel(const float* __restrict__ W, unsigned short* __restrict__ Wb,
                            const float* __restrict__ ctx, const float* __restrict__ Wc,
                            const float* __restrict__ bc, const float* __restrict__ bw,
                            float* __restrict__ cb) {
    __shared__ float row[C_];
    int blk = blockIdx.x, t = threadIdx.x;
    if (blk < 128) {
        int i = (blk * 256 + t) * 4;
        float4 v = *(const float4*)(W + i);
        *(uint2*)(Wb + i) = f4_to_bf4(v);
    } else {
        int b = blk - 128;
        row[t] = ctx[b * C_ + t];
        row[t + 256] = ctx[b * C_ + t + 256];
        __syncthreads();
        const float4* w4 = (const float4*)(Wc + (size_t)t * C_);
        const float4* x4 = (const float4*)row;
        float acc = 0.f;
        #pragma unroll 4
        for (int c = 0; c < C_ / 4; ++c) {
            float4 w = w4[c], x = x4[c];
            acc += w.x * x.x + w.y * x.y + w.z * x.z + w.w * x.w;
        }
        cb[b * H_ + t] = acc + bc[t] + bw[t];
    }
}

// ---- main: scores[b,s] = w_hidden . tanh(embeds[b,s]@W_word^T + cb[b]) ----
// Mixed staging: A (fp32) via register roundtrip + convert-once into padded LDS
// (single ds_read_b128 per fragment); B (bf16) via global_load_lds DMA into
// XOR-swizzled unpadded LDS (chunk p of row r = global chunk p^(r&7)).
// B DMA issued FIRST so its HBM latency hides under A's staging VALU.
#define BM 128
#define BN 256
#define BK 64
#define LDT 72   // padded LDS row stride for A (shorts)

__global__ __launch_bounds__(512) void scores_kernel(
    const float* __restrict__ A,            // [B*S, E] fp32
    const unsigned short* __restrict__ Wb,  // [H, E] bf16
    const float* __restrict__ cb,           // [B, H]
    const float* __restrict__ wh,           // [H]
    const int*   __restrict__ lens,         // [B]
    float* __restrict__ scores)             // [B*S]
{
    __shared__ __align__(16) unsigned short At[BM * LDT];   // 18.4 KB, padded
    __shared__ __align__(16) unsigned short Bt[BN * 64];    // 32 KB, DMA target (no pad)
    __shared__ float sblk[BM];
    int t = threadIdx.x;
    int m0 = blockIdx.x * BM;
    int b  = m0 >> 11;   // /S_
    int ms = m0 & (S_ - 1);
    if (ms >= lens[b]) return;   // fully-masked slab: dead work

    int w = t >> 6, lane = t & 63, quad = lane >> 4, lm = lane & 15;
    int wm = (w & 1) * 64, wn = (w >> 1) * 64;

    if (t < BM) sblk[t] = 0.f;

    f32x4 acc[4][4] = {};

    int arow = t >> 4, acol = (t & 15) * 4;  // A staging: 32 rows/sweep, 4 sweeps
    int la8 = lane >> 3, lc8 = lane & 7;     // B DMA: 8 rows/inst, 8 chunks/row

    for (int k0 = 0; k0 < E_; k0 += BK) {
        // B: 8 waves x 4 DMA insts -> 256 rows x 128 B (issued first, stays in flight)
        #pragma unroll
        for (int j = 0; j < 4; ++j) {
            int r  = (w << 5) + (j << 3) + la8;
            int cg = (lc8 ^ (r & 7)) << 3;               // swizzled global short offset
            async16(Wb + (size_t)r * E_ + k0 + cg,
                    (char*)Bt + (((w << 5) + (j << 3)) << 7));
        }
        // A: register roundtrip, convert once at staging
        #pragma unroll
        for (int i = 0; i < 4; ++i) {
            int r = arow + i * 32;
            float4 v = *(const float4*)(A + (size_t)(m0 + r) * E_ + k0 + acol);
            *(uint2*)(At + r * LDT + acol) = f4_to_bf4(v);
        }
        __syncthreads();
        #pragma unroll
        for (int ks = 0; ks < 2; ++ks) {
            s16x8 af[4], bfr[4];
            #pragma unroll
            for (int i = 0; i < 4; ++i)
                af[i] = *(const s16x8*)(At + (wm + i * 16 + lm) * LDT + ks * 32 + quad * 8);
            #pragma unroll
            for (int i = 0; i < 4; ++i) {
                int r = wn + i * 16 + lm;
                int c = (ks * 4 + quad) ^ (r & 7);
                bfr[i] = *(const s16x8*)(Bt + r * 64 + c * 8);
            }
            #pragma unroll
            for (int mi = 0; mi < 4; ++mi)
                #pragma unroll
                for (int ni = 0; ni < 4; ++ni)
                    acc[mi][ni] = __builtin_amdgcn_mfma_f32_16x16x32_bf16(
                        af[mi], bfr[ni], acc[mi][ni], 0, 0, 0);
        }
        __syncthreads();
    }

    float wv[4], cbv[4];
    #pragma unroll
    for (int ni = 0; ni < 4; ++ni) {
        int n = wn + ni * 16 + lm;
        wv[ni]  = wh[n];
        cbv[ni] = cb[b * H_ + n];
    }
    #pragma unroll
    for (int mi = 0; mi < 4; ++mi) {
        #pragma unroll
        for (int r = 0; r < 4; ++r) {
            float p = 0.f;
            #pragma unroll
            for (int ni = 0; ni < 4; ++ni) {
                float x = acc[mi][ni][r] + cbv[ni];
                x = fminf(fmaxf(x, -15.f), 15.f);
                float e = __expf(2.f * x);
                float th = 1.f - 2.f * __builtin_amdgcn_rcpf(e + 1.f);
                p += wv[ni] * th;
            }
            #pragma unroll
            for (int off = 8; off >= 1; off >>= 1)
                p += __shfl_xor(p, off);
            if (lm == 0)
                atomicAdd(&sblk[wm + mi * 16 + quad * 4 + r], p);
        }
    }
    __syncthreads();
    if (t < BM) scores[m0 + t] = sblk[t];
}

// ---- masked softmax over s<len; attn=0 for s>=len. Also zeroes feat[b,:]
// (wsum accumulates with atomics and runs after this in stream order).
__global__ void softmax_kernel(const int* __restrict__ lens, float* __restrict__ attn,
                               float* __restrict__ feat) {
    __shared__ float redm[4], redt[4];
    int b = blockIdx.x, t = threadIdx.x;
    int len = lens[b];
    float* sc = attn + (size_t)b * S_;
    feat[b * E_ + t] = 0.f;
    feat[b * E_ + 256 + t] = 0.f;
    float v[8];
    #pragma unroll
    for (int i = 0; i < 8; ++i) {
        int s = t + i * 256;
        v[i] = (s < len) ? sc[s] : -1e30f;
    }
    float m = -1e30f;
    #pragma unroll
    for (int i = 0; i < 8; ++i) m = fmaxf(m, v[i]);
    #pragma unroll
    for (int off = 32; off >= 1; off >>= 1) m = fmaxf(m, __shfl_xor(m, off));
    if ((t & 63) == 0) redm[t >> 6] = m;
    __syncthreads();
    m = fmaxf(fmaxf(redm[0], redm[1]), fmaxf(redm[2], redm[3]));
    float e[8]; float tm = 0.f;
    #pragma unroll
    for (int i = 0; i < 8; ++i) {
        int s = t + i * 256;
        e[i] = (s < len) ? __expf(v[i] - m) : 0.f;
        tm += e[i];
    }
    #pragma unroll
    for (int off = 32; off >= 1; off >>= 1) tm += __shfl_xor(tm, off);
    if ((t & 63) == 0) redt[t >> 6] = tm;
    __syncthreads();
    tm = redt[0] + redt[1] + redt[2] + redt[3];
    float sfac = 1.f / tm;
    #pragma unroll
    for (int i = 0; i < 8; ++i) {
        int s = t + i * 256;
        sc[s] = e[i] * sfac;
    }
}

// ---- attention_features[b,e] = sum_{s<len} attn[b,s]*embeds[b,s,e] ----
__global__ __launch_bounds__(512) void wsum_kernel(
    const float* __restrict__ A, const float* __restrict__ attn,
    const int* __restrict__ lens, float* __restrict__ out) {
    int b = blockIdx.y;
    int len = lens[b];
    int s0 = blockIdx.x * 128;
    if (s0 >= len) return;
    int send = s0 + 128; if (send > len) send = len;
    int t  = threadIdx.x;
    int e4 = t & 127;   // float4 column
    int sr = t >> 7;    // row group 0..3
    const float* ap = attn + (size_t)b * S_;
    f32x4 acc = {0.f, 0.f, 0.f, 0.f};
    const float* base = A + (size_t)b * S_ * E_;
    for (int s = s0 + sr; s < send; s += 4) {
        float wgt = ap[s];
        f32x4 v = *(const f32x4*)(base + (size_t)s * E_ + e4 * 4);
        acc += wgt * v;
    }
    __shared__ f32x4 red[4][128];
    red[sr][e4] = acc;
    __syncthreads();
    if (t < 128) {
        f32x4 tot = red[0][t] + red[1][t] + red[2][t] + red[3][t];
        float* o = out + (size_t)b * E_ + t * 4;
        atomicAdd(o + 0, tot[0]);
        atomicAdd(o + 1, tot[1]);
        atomicAdd(o + 2, tot[2]);
        atomicAdd(o + 3, tot[3]);
    }
}

extern "C" void kernel_launch(void* const* d_in, const int* in_sizes, int n_in,
                              void* d_out, int out_size, void* d_ws, size_t ws_size,
                              hipStream_t stream) {
    const float* embeds = (const float*)d_in[0];
    const int*   lens   = (const int*)d_in[1];
    const float* ctx    = (const float*)d_in[2];
    const float* Ww     = (const float*)d_in[3];
    const float* bw     = (const float*)d_in[4];
    const float* Wc     = (const float*)d_in[5];
    const float* bc     = (const float*)d_in[6];
    const float* wh     = (const float*)d_in[7];
    float* out  = (float*)d_out;
    float* feat = out;                 // [B, E]
    float* attn = out + B_ * E_;       // [B, S] (raw scores, then attn; 0 for s>=len)

    unsigned short* Wb = (unsigned short*)d_ws;                                  // 256 KB
    float* cb = (float*)((char*)d_ws + (size_t)H_ * E_ * sizeof(unsigned short)); // 64 KB

    prep_kernel<<<192, 256, 0, stream>>>(Ww, Wb, ctx, Wc, bc, bw, cb);
    scores_kernel<<<dim3(B_ * S_ / BM), 512, 0, stream>>>(embeds, Wb, cb, wh, lens, attn);
    softmax_kernel<<<B_, 256, 0, stream>>>(lens, attn, feat);
    wsum_kernel<<<dim3(S_ / 128, B_), 512, 0, stream>>>(embeds, attn, lens, feat);
}